// Round 7
// baseline (3359.557 us; speedup 1.0000x reference)
//
#include <hip/hip_runtime.h>
#include <math.h>

// Model constants: B=32, T=50000, P=100, D=512, H=16, L=6, C=256
// SCALES=[1,2,4], HS=5 heads/scale, KD=32, N=500 patches, FF=2048, EPS=1e-3.
//
// KEY INSIGHT (round 0, verified): first layernorm is over a size-1 axis ->
// output == ln_in_b[0] everywhere. h is batch-independent; network runs once
// on (500 x 512); final row broadcast x32.
//
// Round 7: R6's hipLaunchCooperativeKernel failed at launch (output never
// written). Same persistent mega-kernel, but plain launch + software grid
// barrier: agent-scope atomics (acq_rel arrive / acquire spin) force L2
// writeback+invalidate across non-coherent XCD L2s; 256 blocks x 25.6KB LDS
// = guaranteed co-residency (1 block/CU). Barrier zeroed via hipMemsetAsync.

#define DD 512
#define NN 500
#define HSC 5
#define KDD 32
#define QKVN 160
#define QKV3 480
#define FF 2048
#define NL 6
#define NC 256
#define NB 32
#define LNEPS 1e-3f
#define BM 128
#define BN 64
#define KCH 32
#define NBLK 256

#define AOFF1 256000
#define AOFF2 384000
#define RTOT 875
#define OSZ 140000
#define MLSZ 4384

__device__ __forceinline__ float gelu_exact(float x) {
    return 0.5f * x * (1.0f + erff(x * 0.70710678118654752f));
}

union SMem {
    struct { float As[KCH][132]; float Bs[KCH][68]; } g;   // 25.6 KB (gemm)
    struct { float Ks[64][36]; float Vs[64][36]; } a;      // 18.4 KB (attn)
    struct { float s1[4], s2[4], mb[2]; } ln;
    struct { float gs[DD]; float r[4]; float bmx, bsum; } hd;
};

// ======================= software grid barrier =======================
// bar[0]=arrive, bar[1]=generation. __syncthreads drains each wave's stores
// to its XCD L2; acq_rel arrival does wbl2 (release) + inv (acquire); the
// spin's acquire load invalidates so post-barrier reads see remote writes.
__device__ __forceinline__ void gbar(unsigned* bar) {
    __syncthreads();
    if (threadIdx.x == 0) {
        unsigned gen = __hip_atomic_load(bar + 1, __ATOMIC_RELAXED,
                                         __HIP_MEMORY_SCOPE_AGENT);
        unsigned prev = __hip_atomic_fetch_add(bar, 1u, __ATOMIC_ACQ_REL,
                                               __HIP_MEMORY_SCOPE_AGENT);
        if (prev == NBLK - 1u) {
            __hip_atomic_store(bar, 0u, __ATOMIC_RELAXED,
                               __HIP_MEMORY_SCOPE_AGENT);
            __hip_atomic_fetch_add(bar + 1, 1u, __ATOMIC_RELEASE,
                                   __HIP_MEMORY_SCOPE_AGENT);
        } else {
            int spins = 0;
            while (__hip_atomic_load(bar + 1, __ATOMIC_ACQUIRE,
                                     __HIP_MEMORY_SCOPE_AGENT) == gen
                   && ++spins < (1 << 22))
                __builtin_amdgcn_s_sleep(2);
        }
    }
    __syncthreads();
}

// ======================= GEMM core =======================
__device__ __forceinline__ void gc_stage(
        const float* __restrict__ A, int lda, int pool_s, float inv_pool, int gather,
        const float* __restrict__ B, int ldb,
        int M, int N, int bm, int bn, int k0,
        int am, int akv, int bk, int bn4, float4* aR, float4* bR) {
    if (!gather) {
        #pragma unroll
        for (int p = 0; p < 4; ++p) {
            int row = bm + p * 32 + am;
            float4 v = make_float4(0.f, 0.f, 0.f, 0.f);
            if (row < M) {
                const float* ap = A + (size_t)row * pool_s * lda + k0 + akv * 4;
                v = *(const float4*)ap;
                for (int t = 1; t < pool_s; ++t) {
                    float4 u = *(const float4*)(ap + (size_t)t * lda);
                    v.x += u.x; v.y += u.y; v.z += u.z; v.w += u.w;
                }
                v.x *= inv_pool; v.y *= inv_pool; v.z *= inv_pool; v.w *= inv_pool;
            }
            aR[p] = v;
        }
    } else {
        int si = k0 >> 9;
        int dd0 = k0 & (DD - 1);
        const float* ap0 = A + (si == 0 ? 0 : (si == 1 ? AOFF1 : AOFF2));
        #pragma unroll
        for (int p = 0; p < 4; ++p) {
            int row = bm + p * 32 + am;
            float4 v = make_float4(0.f, 0.f, 0.f, 0.f);
            if (row < M)
                v = *(const float4*)(ap0 + (size_t)(row >> si) * DD + dd0 + akv * 4);
            aR[p] = v;
        }
    }
    int col = bn + bn4 * 4;
    #pragma unroll
    for (int p = 0; p < 2; ++p) {
        int kk = p * 16 + bk;
        float4 v = make_float4(0.f, 0.f, 0.f, 0.f);
        if (col < N) v = *(const float4*)(B + (size_t)(k0 + kk) * ldb + col);
        bR[p] = v;
    }
}

__device__ __forceinline__ void gemm_core(
        SMem& sm,
        const float* __restrict__ A, int lda, int pool_s, int gather,
        const float* __restrict__ B, int ldb,
        int M, int N, int bm, int bn, int ks, int kend,
        float (&acc)[8][4]) {
    int tid = threadIdx.x;
    int am = tid >> 3, akv = tid & 7;
    int bk = tid >> 4, bn4 = tid & 15;
    float inv_pool = 1.0f / (float)pool_s;

    float4 aR[4], bR[2];
    gc_stage(A, lda, pool_s, inv_pool, gather, B, ldb, M, N, bm, bn, ks,
             am, akv, bk, bn4, aR, bR);
    int nch = (kend - ks) / KCH;
    int tx = tid & 15, ty = tid >> 4;
    for (int c = 0; c < nch; ++c) {
        __syncthreads();
        #pragma unroll
        for (int p = 0; p < 4; ++p) {
            int m = p * 32 + am;
            sm.g.As[akv * 4 + 0][m] = aR[p].x;
            sm.g.As[akv * 4 + 1][m] = aR[p].y;
            sm.g.As[akv * 4 + 2][m] = aR[p].z;
            sm.g.As[akv * 4 + 3][m] = aR[p].w;
        }
        #pragma unroll
        for (int p = 0; p < 2; ++p)
            *(float4*)&sm.g.Bs[p * 16 + bk][bn4 * 4] = bR[p];
        __syncthreads();
        if (c + 1 < nch)
            gc_stage(A, lda, pool_s, inv_pool, gather, B, ldb, M, N, bm, bn,
                     ks + (c + 1) * KCH, am, akv, bk, bn4, aR, bR);
        #pragma unroll
        for (int kk = 0; kk < KCH; ++kk) {
            float4 b  = *(const float4*)&sm.g.Bs[kk][tx * 4];
            float4 al = *(const float4*)&sm.g.As[kk][ty * 8];
            float4 ah = *(const float4*)&sm.g.As[kk][ty * 8 + 4];
            float a8[8] = {al.x, al.y, al.z, al.w, ah.x, ah.y, ah.z, ah.w};
            float b4[4] = {b.x, b.y, b.z, b.w};
            #pragma unroll
            for (int u = 0; u < 8; ++u)
                #pragma unroll
                for (int v = 0; v < 4; ++v)
                    acc[u][v] += a8[u] * b4[v];
        }
    }
}

#define ACC_INIT(acc) { _Pragma("unroll") for (int u=0;u<8;++u) _Pragma("unroll") for (int v=0;v<4;++v) acc[u][v]=0.f; }

struct Params {
    const float *ln_in_b, *patch_W, *patch_b, *pos_emb;
    const float *Wq, *bq, *Wk, *bk, *Wv, *bv, *Wo, *bo, *Wc, *bc;
    const float *ln1_g, *ln1_b, *W1, *b1, *W2, *b2, *ln2_g, *ln2_b;
    const float *head_W, *head_b;
    float *out;
    float *h, *csum, *qkvAll, *oAll, *aAll, *f, *part, *headp;
    float *oPart, *mPart, *lPart, *qkvP;
    unsigned *bar;
};

// ======================= stage bodies =======================
__device__ void st_qkv_part(SMem& sm, const Params& p, int l, int u) {
    int scale, sp, y, x;
    if (u < 144)      { scale = 0; sp = u / 36; int r = u % 36; y = r / 9; x = r % 9; }
    else if (u < 216) { scale = 1; int v = u - 144; sp = v / 18; int r = v % 18; y = r / 9; x = r % 9; }
    else              { scale = 2; int v = u - 216; sp = v / 9; x = v % 9; y = 0; }
    int n = NN >> scale;
    int pool_s = 1 << scale;
    int bm = y * BM;
    int which = x / 3;
    int bn = (x % 3) * BN;
    size_t w = (size_t)(l * 3 + scale);
    const float* W = (which == 0) ? p.Wq : ((which == 1) ? p.Wk : p.Wv);
    float* outb = p.qkvP + (size_t)sp * 420000
                + (scale == 0 ? 0 : (scale == 1 ? 240000 : 360000));
    float acc[8][4];
    ACC_INIT(acc);
    gemm_core(sm, p.h, DD, pool_s, 0, W + w * DD * QKVN, QKVN, n, QKVN, bm, bn,
              sp * 128, sp * 128 + 128, acc);
    int tid = threadIdx.x, tx = tid & 15, ty = tid >> 4;
    int col = bn + tx * 4;
    if (col < QKVN) {
        #pragma unroll
        for (int uu = 0; uu < 8; ++uu) {
            int row = bm + ty * 8 + uu;
            if (row < n) {
                float4 o;
                o.x = acc[uu][0]; o.y = acc[uu][1]; o.z = acc[uu][2]; o.w = acc[uu][3];
                *(float4*)&outb[(size_t)row * QKV3 + which * QKVN + col] = o;
            }
        }
    }
}

__device__ void st_qkv_reduce(const Params& p, int l, int gtid, int gstride) {
    const float4* p0 = (const float4*)p.qkvP;
    float4* dst = (float4*)p.qkvAll;
    for (int i4 = gtid; i4 < 105000; i4 += gstride) {
        float4 a = p0[i4], b = p0[105000 + i4], c = p0[210000 + i4], d = p0[315000 + i4];
        int scale = (i4 < 60000) ? 0 : (i4 < 90000 ? 1 : 2);
        int rr = i4 % 120;
        int which = rr / 40, col4 = rr - which * 40;
        const float* bias = (which == 0) ? p.bq : (which == 1 ? p.bk : p.bv);
        float4 bb = ((const float4*)(bias + (size_t)(l * 3 + scale) * QKVN))[col4];
        float4 o;
        o.x = a.x + b.x + c.x + d.x + bb.x;
        o.y = a.y + b.y + c.y + d.y + bb.y;
        o.z = a.z + b.z + c.z + d.z + bb.z;
        o.w = a.w + b.w + c.w + d.w + bb.w;
        dst[i4] = o;
    }
}

__device__ void st_attn(SMem& sm, const Params& p, int u) {
    int scale, sp, qt, hh;
    if (u < 160)      { scale = 0; sp = u / 40; int r = u % 40; hh = r / 8; qt = r % 8; }
    else if (u < 200) { scale = 1; int v = u - 160; sp = v / 20; int r = v % 20; hh = r / 4; qt = r % 4; }
    else              { scale = 2; int v = u - 200; sp = 0; hh = v / 2; qt = v % 2; }
    int n = NN >> scale;
    int ks = sp * 128;
    int ke = min(n, ks + 128);
    const float* qkv = p.qkvAll + (scale == 0 ? 0 : (scale == 1 ? 240000 : 360000));
    int rowb = (scale == 0 ? 0 : (scale == 1 ? 500 : 750));

    int tid = threadIdx.x;
    int kg = tid & 7, qq = tid >> 3;
    int q0 = qt * 64 + qq, q1 = q0 + 32;
    bool ok0 = q0 < n, ok1 = q1 < n;

    float qa[32], qb[32];
    {
        const float* pa = qkv + (size_t)(ok0 ? q0 : 0) * QKV3 + hh * KDD;
        const float* pb = qkv + (size_t)(ok1 ? q1 : 0) * QKV3 + hh * KDD;
        #pragma unroll
        for (int c4 = 0; c4 < 8; ++c4) {
            float4 v0 = *(const float4*)(pa + c4 * 4);
            float4 v1 = *(const float4*)(pb + c4 * 4);
            qa[c4*4] = v0.x; qa[c4*4+1] = v0.y; qa[c4*4+2] = v0.z; qa[c4*4+3] = v0.w;
            qb[c4*4] = v1.x; qb[c4*4+1] = v1.y; qb[c4*4+2] = v1.z; qb[c4*4+3] = v1.w;
        }
    }
    float o0[32], o1[32];
    #pragma unroll
    for (int c = 0; c < 32; ++c) { o0[c] = 0.f; o1[c] = 0.f; }
    float m0 = -1e30f, m1 = -1e30f, l0 = 0.f, l1 = 0.f;
    int srow = tid >> 2, scol = tid & 3;

    for (int kc = ks; kc < ke; kc += 64) {
        __syncthreads();
        int krow = kc + srow;
        bool ok = krow < ke;
        const float* kp = qkv + (size_t)(ok ? krow : 0) * QKV3 + QKVN + hh * KDD;
        #pragma unroll
        for (int half = 0; half < 2; ++half) {
            int cc = (half * 4 + scol) * 4;
            float4 kv = ok ? *(const float4*)(kp + cc) : make_float4(0.f,0.f,0.f,0.f);
            float4 vv = ok ? *(const float4*)(kp + QKVN + cc) : make_float4(0.f,0.f,0.f,0.f);
            sm.a.Ks[srow][cc] = kv.x; sm.a.Ks[srow][cc+1] = kv.y;
            sm.a.Ks[srow][cc+2] = kv.z; sm.a.Ks[srow][cc+3] = kv.w;
            sm.a.Vs[srow][cc] = vv.x; sm.a.Vs[srow][cc+1] = vv.y;
            sm.a.Vs[srow][cc+2] = vv.z; sm.a.Vs[srow][cc+3] = vv.w;
        }
        __syncthreads();

        float pp0[8], pp1[8];
        float cm = -1e30f;
        #pragma unroll
        for (int jj = 0; jj < 8; ++jj) {
            int j = jj * 8 + kg;
            float s0 = 0.f, s1 = 0.f;
            #pragma unroll
            for (int c4 = 0; c4 < 8; ++c4) {
                float4 kv = *(const float4*)&sm.a.Ks[j][c4 * 4];
                s0 += qa[c4*4]*kv.x + qa[c4*4+1]*kv.y + qa[c4*4+2]*kv.z + qa[c4*4+3]*kv.w;
                s1 += qb[c4*4]*kv.x + qb[c4*4+1]*kv.y + qb[c4*4+2]*kv.z + qb[c4*4+3]*kv.w;
            }
            s0 *= 0.17677669529663687f;
            s1 *= 0.17677669529663687f;
            if (kc + j >= ke) { s0 = -1e30f; s1 = -1e30f; }
            pp0[jj] = s0; pp1[jj] = s1;
            cm = fmaxf(cm, fmaxf(s0, s1));
        }
        cm = fmaxf(cm, __shfl_xor(cm, 1));
        cm = fmaxf(cm, __shfl_xor(cm, 2));
        cm = fmaxf(cm, __shfl_xor(cm, 4));
        float mn0 = fmaxf(m0, cm), mn1 = fmaxf(m1, cm);
        float al0 = expf(m0 - mn0), al1 = expf(m1 - mn1);
        m0 = mn0; m1 = mn1;
        float ls0 = 0.f, ls1 = 0.f;
        #pragma unroll
        for (int jj = 0; jj < 8; ++jj) {
            pp0[jj] = expf(pp0[jj] - mn0); ls0 += pp0[jj];
            pp1[jj] = expf(pp1[jj] - mn1); ls1 += pp1[jj];
        }
        l0 = l0 * al0 + ls0;
        l1 = l1 * al1 + ls1;
        #pragma unroll
        for (int c = 0; c < 32; ++c) { o0[c] *= al0; o1[c] *= al1; }
        #pragma unroll
        for (int jj = 0; jj < 8; ++jj) {
            int j = jj * 8 + kg;
            float w0 = pp0[jj], w1 = pp1[jj];
            #pragma unroll
            for (int c4 = 0; c4 < 8; ++c4) {
                float4 vv = *(const float4*)&sm.a.Vs[j][c4 * 4];
                o0[c4*4]   += w0*vv.x; o0[c4*4+1] += w0*vv.y;
                o0[c4*4+2] += w0*vv.z; o0[c4*4+3] += w0*vv.w;
                o1[c4*4]   += w1*vv.x; o1[c4*4+1] += w1*vv.y;
                o1[c4*4+2] += w1*vv.z; o1[c4*4+3] += w1*vv.w;
            }
        }
    }
    #pragma unroll
    for (int st = 1; st < 8; st <<= 1) {
        l0 += __shfl_xor(l0, st);
        l1 += __shfl_xor(l1, st);
        #pragma unroll
        for (int c = 0; c < 32; ++c) {
            o0[c] += __shfl_xor(o0[c], st);
            o1[c] += __shfl_xor(o1[c], st);
        }
    }
    if (kg == 0) {
        float* ob = p.oPart + (size_t)sp * OSZ;
        if (ok0) {
            int r = rowb + q0;
            float* op = ob + (size_t)r * QKVN + hh * KDD;
            #pragma unroll
            for (int c4 = 0; c4 < 8; ++c4) {
                float4 v; v.x = o0[c4*4]; v.y = o0[c4*4+1]; v.z = o0[c4*4+2]; v.w = o0[c4*4+3];
                *(float4*)(op + c4 * 4) = v;
            }
            p.mPart[sp * MLSZ + r * HSC + hh] = m0;
            p.lPart[sp * MLSZ + r * HSC + hh] = l0;
        }
        if (ok1) {
            int r = rowb + q1;
            float* op = ob + (size_t)r * QKVN + hh * KDD;
            #pragma unroll
            for (int c4 = 0; c4 < 8; ++c4) {
                float4 v; v.x = o1[c4*4]; v.y = o1[c4*4+1]; v.z = o1[c4*4+2]; v.w = o1[c4*4+3];
                *(float4*)(op + c4 * 4) = v;
            }
            p.mPart[sp * MLSZ + r * HSC + hh] = m1;
            p.lPart[sp * MLSZ + r * HSC + hh] = l1;
        }
    }
}

__device__ void st_attn_combine(const Params& p, int gtid, int gstride) {
    for (int idx = gtid; idx < OSZ; idx += gstride) {
        int rh = idx >> 5;
        int r = rh / HSC, hh = rh - r * HSC;
        int scale = (r < 500) ? 0 : (r < 750 ? 1 : 2);
        int ns = 4 >> scale;
        float M = -1e30f;
        for (int s = 0; s < ns; ++s) M = fmaxf(M, p.mPart[s * MLSZ + r * HSC + hh]);
        float L = 0.f, val = 0.f;
        for (int s = 0; s < ns; ++s) {
            float wgt = expf(p.mPart[s * MLSZ + r * HSC + hh] - M);
            L += wgt * p.lPart[s * MLSZ + r * HSC + hh];
            val += wgt * p.oPart[(size_t)s * OSZ + idx];
        }
        p.oAll[idx] = val / L;
    }
}

__device__ void st_wo(SMem& sm, const Params& p, int l, int u) {
    int z, x, y;
    if (u < 32)      { z = 0; x = u % 8; y = u / 8; }
    else if (u < 48) { z = 1; int v = u - 32; x = v % 8; y = v / 8; }
    else             { z = 2; int v = u - 48; x = v % 8; y = 0; }
    int n = NN >> z;
    int bm = y * BM, bn = x * BN;
    size_t w = (size_t)(l * 3 + z);
    const float* A = p.oAll + (z == 0 ? 0 : (z == 1 ? 80000 : 120000));
    float* C = p.aAll + (z == 0 ? 0 : (z == 1 ? AOFF1 : AOFF2));
    const float* bias = p.bo + w * DD;
    float acc[8][4];
    ACC_INIT(acc);
    gemm_core(sm, A, QKVN, 1, 0, p.Wo + w * QKVN * DD, DD, n, DD, bm, bn, 0, QKVN, acc);
    int tid = threadIdx.x, tx = tid & 15, ty = tid >> 4;
    int col = bn + tx * 4;
    #pragma unroll
    for (int uu = 0; uu < 8; ++uu) {
        int row = bm + ty * 8 + uu;
        if (row < n) {
            float4 o;
            o.x = acc[uu][0] + bias[col];     o.y = acc[uu][1] + bias[col + 1];
            o.z = acc[uu][2] + bias[col + 2]; o.w = acc[uu][3] + bias[col + 3];
            *(float4*)&C[(size_t)row * DD + col] = o;
        }
    }
}

__device__ void st_comb(SMem& sm, const Params& p, const float* Wc, int u) {
    int x = u & 7, y = (u >> 3) & 3, zz = u >> 5;
    int bm = y * BM, bn = x * BN;
    float acc[8][4];
    ACC_INIT(acc);
    gemm_core(sm, p.aAll, DD, 1, 1, Wc, DD, NN, DD, bm, bn, zz * 256, zz * 256 + 256, acc);
    float* pz = p.part + (size_t)zz * NN * DD;
    int tid = threadIdx.x, tx = tid & 15, ty = tid >> 4;
    int col = bn + tx * 4;
    #pragma unroll
    for (int uu = 0; uu < 8; ++uu) {
        int row = bm + ty * 8 + uu;
        if (row < NN) {
            float4 o;
            o.x = acc[uu][0]; o.y = acc[uu][1]; o.z = acc[uu][2]; o.w = acc[uu][3];
            *(float4*)&pz[(size_t)row * DD + col] = o;
        }
    }
}

__device__ void st_w1(SMem& sm, const Params& p, const float* W1, int u) {
    int x = u & 31, y = (u >> 5) & 3, sp = u >> 7;
    int bm = y * BM, bn = x * BN;
    float acc[8][4];
    ACC_INIT(acc);
    gemm_core(sm, p.h, DD, 1, 0, W1, FF, NN, FF, bm, bn, sp * 256, sp * 256 + 256, acc);
    float* pz = p.part + (size_t)sp * NN * FF;
    int tid = threadIdx.x, tx = tid & 15, ty = tid >> 4;
    int col = bn + tx * 4;
    #pragma unroll
    for (int uu = 0; uu < 8; ++uu) {
        int row = bm + ty * 8 + uu;
        if (row < NN) {
            float4 o;
            o.x = acc[uu][0]; o.y = acc[uu][1]; o.z = acc[uu][2]; o.w = acc[uu][3];
            *(float4*)&pz[(size_t)row * FF + col] = o;
        }
    }
}

__device__ void st_w1_reduce(const Params& p, const float* b1, int gtid, int gstride) {
    const float4* pa = (const float4*)p.part;
    const float4* pb = (const float4*)(p.part + NN * FF);
    const float4* bb = (const float4*)b1;
    float4* dst = (float4*)p.f;
    for (int i4 = gtid; i4 < 256000; i4 += gstride) {
        float4 a = pa[i4], b = pb[i4], c = bb[i4 & 511];
        float4 o;
        o.x = gelu_exact(a.x + b.x + c.x);
        o.y = gelu_exact(a.y + b.y + c.y);
        o.z = gelu_exact(a.z + b.z + c.z);
        o.w = gelu_exact(a.w + b.w + c.w);
        dst[i4] = o;
    }
}

__device__ void st_w2(SMem& sm, const Params& p, const float* W2, int u) {
    int x = u & 7, y = (u >> 3) & 3, zz = u >> 5;
    int bm = y * BM, bn = x * BN;
    float acc[8][4];
    ACC_INIT(acc);
    gemm_core(sm, p.f, FF, 1, 0, W2, DD, NN, DD, bm, bn, zz * 256, zz * 256 + 256, acc);
    float* pz = p.part + (size_t)zz * NN * DD;
    int tid = threadIdx.x, tx = tid & 15, ty = tid >> 4;
    int col = bn + tx * 4;
    #pragma unroll
    for (int uu = 0; uu < 8; ++uu) {
        int row = bm + ty * 8 + uu;
        if (row < NN) {
            float4 o;
            o.x = acc[uu][0]; o.y = acc[uu][1]; o.z = acc[uu][2]; o.w = acc[uu][3];
            *(float4*)&pz[(size_t)row * DD + col] = o;
        }
    }
}

// 256 threads, one row: thread t handles cols t and t+256
__device__ void st_reduce_add_ln(SMem& sm, const Params& p, int S,
                                 const float* bias, const float* gw,
                                 const float* bw, int row) {
    int t = threadIdx.x;
    size_t i0 = (size_t)row * DD + t, i1 = i0 + 256;
    float x0 = p.h[i0] + bias[t];
    float x1 = p.h[i1] + bias[t + 256];
    for (int s = 0; s < S; ++s) {
        x0 += p.part[(size_t)s * NN * DD + i0];
        x1 += p.part[(size_t)s * NN * DD + i1];
    }
    float sum = x0 + x1, sq = x0 * x0 + x1 * x1;
    for (int off = 32; off; off >>= 1) {
        sum += __shfl_down(sum, off);
        sq  += __shfl_down(sq,  off);
    }
    int lane = t & 63, wv = t >> 6;
    if (lane == 0) { sm.ln.s1[wv] = sum; sm.ln.s2[wv] = sq; }
    __syncthreads();
    if (t == 0) {
        float a = sm.ln.s1[0] + sm.ln.s1[1] + sm.ln.s1[2] + sm.ln.s1[3];
        float b = sm.ln.s2[0] + sm.ln.s2[1] + sm.ln.s2[2] + sm.ln.s2[3];
        float mean = a / (float)DD;
        float var = b / (float)DD - mean * mean;
        sm.ln.mb[0] = mean;
        sm.ln.mb[1] = rsqrtf(var + LNEPS);
    }
    __syncthreads();
    float mean = sm.ln.mb[0], inv = sm.ln.mb[1];
    p.h[i0] = (x0 - mean) * inv * gw[t] + bw[t];
    p.h[i1] = (x1 - mean) * inv * gw[t + 256] + bw[t + 256];
    __syncthreads();
}

__device__ void st_head(SMem& sm, const Params& p) {
    int t = threadIdx.x;
    for (int d = t; d < DD; d += 256) {
        float s = 0.f;
        #pragma unroll
        for (int q = 0; q < 25; ++q) s += p.headp[(size_t)q * DD + d];
        sm.hd.gs[d] = s / (float)NN;
    }
    __syncthreads();
    float acc = p.head_b[t];
    #pragma unroll 16
    for (int d = 0; d < DD; ++d) acc += sm.hd.gs[d] * p.head_W[(size_t)d * NC + t];
    int lane = t & 63, wv = t >> 6;
    float mx = acc;
    for (int off = 32; off; off >>= 1) mx = fmaxf(mx, __shfl_down(mx, off));
    if (lane == 0) sm.hd.r[wv] = mx;
    __syncthreads();
    if (t == 0) sm.hd.bmx = fmaxf(fmaxf(sm.hd.r[0], sm.hd.r[1]), fmaxf(sm.hd.r[2], sm.hd.r[3]));
    __syncthreads();
    float e = expf(acc - sm.hd.bmx);
    float s = e;
    for (int off = 32; off; off >>= 1) s += __shfl_down(s, off);
    if (lane == 0) sm.hd.r[wv] = s;
    __syncthreads();
    if (t == 0) sm.hd.bsum = 1.f / (sm.hd.r[0] + sm.hd.r[1] + sm.hd.r[2] + sm.hd.r[3]);
    __syncthreads();
    float pv = e * sm.hd.bsum;
    for (int b = 0; b < NB; ++b) p.out[(size_t)b * NC + t] = pv;
}

// ======================= mega kernel =======================
__global__ __launch_bounds__(256) void mega(Params p) {
    __shared__ SMem sm;
    int b = blockIdx.x;
    int t = threadIdx.x;
    int gtid = b * 256 + t;
    const int gstride = 256 * 256;

    // S0: colsum (2 blocks)
    if (b < 2) {
        int d = b * 256 + t;
        float s = 0.f;
        for (int q = 0; q < 100; ++q) s += p.patch_W[q * DD + d];
        p.csum[d] = s;
    }
    gbar(p.bar);
    // S1: init h
    {
        float lnb = p.ln_in_b[0];
        for (int i = gtid; i < NN * DD; i += gstride) {
            int d = i & (DD - 1);
            p.h[i] = lnb * p.csum[d] + p.patch_b[d] + p.pos_emb[i];
        }
    }
    gbar(p.bar);

    for (int l = 0; l < NL; ++l) {
        if (b < 252) st_qkv_part(sm, p, l, b);
        gbar(p.bar);
        st_qkv_reduce(p, l, gtid, gstride);
        gbar(p.bar);
        if (b < 210) st_attn(sm, p, b);
        gbar(p.bar);
        st_attn_combine(p, gtid, gstride);
        gbar(p.bar);
        if (b < 56) st_wo(sm, p, l, b);
        gbar(p.bar);
        if (b < 192) st_comb(sm, p, p.Wc + (size_t)l * 3 * DD * DD, b);
        gbar(p.bar);
        for (int u = b; u < NN; u += 256)
            st_reduce_add_ln(sm, p, 6, p.bc + (size_t)l * DD,
                             p.ln1_g + (size_t)l * DD, p.ln1_b + (size_t)l * DD, u);
        gbar(p.bar);
        st_w1(sm, p, p.W1 + (size_t)l * DD * FF, b);
        gbar(p.bar);
        st_w1_reduce(p, p.b1 + (size_t)l * FF, gtid, gstride);
        gbar(p.bar);
        st_w2(sm, p, p.W2 + (size_t)l * FF * DD, b);
        gbar(p.bar);
        for (int u = b; u < NN; u += 256)
            st_reduce_add_ln(sm, p, 8, p.b2 + (size_t)l * DD,
                             p.ln2_g + (size_t)l * DD, p.ln2_b + (size_t)l * DD, u);
        gbar(p.bar);
    }
    // head: col-partial (50 units) then final on block 0
    if (b < 50) {
        int xb = b & 1, yb = b >> 1;
        int col = xb * 256 + t;
        int r0 = yb * 20;
        float s = 0.f;
        #pragma unroll
        for (int r = 0; r < 20; ++r) s += p.h[(size_t)(r0 + r) * DD + col];
        p.headp[(size_t)yb * DD + col] = s;
    }
    gbar(p.bar);
    if (b == 0) st_head(sm, p);
}

extern "C" void kernel_launch(void* const* d_in, const int* in_sizes, int n_in,
                              void* d_out, int out_size, void* d_ws, size_t ws_size,
                              hipStream_t stream) {
    Params p;
    p.ln_in_b = (const float*)d_in[2];
    p.patch_W = (const float*)d_in[3];
    p.patch_b = (const float*)d_in[4];
    p.pos_emb = (const float*)d_in[5];
    p.Wq = (const float*)d_in[6];  p.bq = (const float*)d_in[7];
    p.Wk = (const float*)d_in[8];  p.bk = (const float*)d_in[9];
    p.Wv = (const float*)d_in[10]; p.bv = (const float*)d_in[11];
    p.Wo = (const float*)d_in[12]; p.bo = (const float*)d_in[13];
    p.Wc = (const float*)d_in[14]; p.bc = (const float*)d_in[15];
    p.ln1_g = (const float*)d_in[16]; p.ln1_b = (const float*)d_in[17];
    p.W1 = (const float*)d_in[18]; p.b1 = (const float*)d_in[19];
    p.W2 = (const float*)d_in[20]; p.b2 = (const float*)d_in[21];
    p.ln2_g = (const float*)d_in[22]; p.ln2_b = (const float*)d_in[23];
    p.head_W = (const float*)d_in[24]; p.head_b = (const float*)d_in[25];
    p.out = (float*)d_out;

    float* ws = (float*)d_ws;
    p.h      = ws;
    p.csum   = p.h + 256000;
    p.qkvAll = p.csum + 1024;
    p.oAll   = p.qkvAll + 420000;
    p.aAll   = p.oAll + 140000;
    p.f      = p.aAll + 448000;
    p.part   = p.f + 1024000;
    p.headp  = p.part + 2048000;
    p.oPart  = p.f;
    p.mPart  = p.f + 560000;
    p.lPart  = p.mPart + 4 * MLSZ;
    p.qkvP   = p.part;
    p.bar    = (unsigned*)(p.headp + 12800);

    hipMemsetAsync(p.bar, 0, 64, stream);
    mega<<<dim3(NBLK), dim3(256), 0, stream>>>(p);
}

// Round 8
// 2804.934 us; speedup vs baseline: 1.1977x; 1.1977x over previous
//
#include <hip/hip_runtime.h>
#include <math.h>

// Model constants: B=32, T=50000, P=100, D=512, H=16, L=6, C=256
// SCALES=[1,2,4], HS=5 heads/scale, KD=32, N=500 patches, FF=2048, EPS=1e-3.
//
// KEY INSIGHT (round 0, verified): first layernorm is over a size-1 axis ->
// output == ln_in_b[0] everywhere. h is batch-independent; network runs once
// on (500 x 512); final row broadcast x32.
//
// Round 8: R7's barrier was correct but each spin poll used agent-scope
// ACQUIRE -> buffer_inv per poll x 255 blocks = L2 invalidation storm
// (FETCH 373MB, 40us/barrier, 3336us total). Fix: fences hoisted out of the
// loop — one __threadfence() release before arrival, RELAXED arrival +
// RELAXED spin polls (no cache fence), one __threadfence() after the flip.

#define DD 512
#define NN 500
#define HSC 5
#define KDD 32
#define QKVN 160
#define QKV3 480
#define FF 2048
#define NL 6
#define NC 256
#define NB 32
#define LNEPS 1e-3f
#define BM 128
#define BN 64
#define KCH 32
#define NBLK 256

#define AOFF1 256000
#define AOFF2 384000
#define RTOT 875
#define OSZ 140000
#define MLSZ 4384

__device__ __forceinline__ float gelu_exact(float x) {
    return 0.5f * x * (1.0f + erff(x * 0.70710678118654752f));
}

union SMem {
    struct { float As[KCH][132]; float Bs[KCH][68]; } g;   // 25.6 KB (gemm)
    struct { float Ks[64][36]; float Vs[64][36]; } a;      // 18.4 KB (attn)
    struct { float s1[4], s2[4], mb[2]; } ln;
    struct { float gs[DD]; float r[4]; float bmx, bsum; } hd;
};

// ======================= software grid barrier =======================
// Sense-reversal. Fences hoisted out of the spin: release fence (wbl2) once
// before arrival; RELAXED RMW arrival; RELAXED polls (bypass L2, no inv);
// acquire fence (inv) once after observing the generation flip.
__device__ __forceinline__ void gbar(unsigned* bar) {
    __syncthreads();
    if (threadIdx.x == 0) {
        __threadfence();   // release: drain my XCD L2 to the coherence point
        unsigned gen = __hip_atomic_load(bar + 1, __ATOMIC_RELAXED,
                                         __HIP_MEMORY_SCOPE_AGENT);
        unsigned prev = __hip_atomic_fetch_add(bar, 1u, __ATOMIC_RELAXED,
                                               __HIP_MEMORY_SCOPE_AGENT);
        if (prev == NBLK - 1u) {
            __hip_atomic_store(bar, 0u, __ATOMIC_RELAXED,
                               __HIP_MEMORY_SCOPE_AGENT);
            __hip_atomic_store(bar + 1, gen + 1u, __ATOMIC_RELAXED,
                               __HIP_MEMORY_SCOPE_AGENT);
        } else {
            int spins = 0;
            while (__hip_atomic_load(bar + 1, __ATOMIC_RELAXED,
                                     __HIP_MEMORY_SCOPE_AGENT) == gen
                   && ++spins < (1 << 24))
                __builtin_amdgcn_s_sleep(4);
        }
        __threadfence();   // acquire: invalidate so I see remote XCD writes
    }
    __syncthreads();
}

// ======================= GEMM core =======================
__device__ __forceinline__ void gc_stage(
        const float* __restrict__ A, int lda, int pool_s, float inv_pool, int gather,
        const float* __restrict__ B, int ldb,
        int M, int N, int bm, int bn, int k0,
        int am, int akv, int bk, int bn4, float4* aR, float4* bR) {
    if (!gather) {
        #pragma unroll
        for (int p = 0; p < 4; ++p) {
            int row = bm + p * 32 + am;
            float4 v = make_float4(0.f, 0.f, 0.f, 0.f);
            if (row < M) {
                const float* ap = A + (size_t)row * pool_s * lda + k0 + akv * 4;
                v = *(const float4*)ap;
                for (int t = 1; t < pool_s; ++t) {
                    float4 u = *(const float4*)(ap + (size_t)t * lda);
                    v.x += u.x; v.y += u.y; v.z += u.z; v.w += u.w;
                }
                v.x *= inv_pool; v.y *= inv_pool; v.z *= inv_pool; v.w *= inv_pool;
            }
            aR[p] = v;
        }
    } else {
        int si = k0 >> 9;
        int dd0 = k0 & (DD - 1);
        const float* ap0 = A + (si == 0 ? 0 : (si == 1 ? AOFF1 : AOFF2));
        #pragma unroll
        for (int p = 0; p < 4; ++p) {
            int row = bm + p * 32 + am;
            float4 v = make_float4(0.f, 0.f, 0.f, 0.f);
            if (row < M)
                v = *(const float4*)(ap0 + (size_t)(row >> si) * DD + dd0 + akv * 4);
            aR[p] = v;
        }
    }
    int col = bn + bn4 * 4;
    #pragma unroll
    for (int p = 0; p < 2; ++p) {
        int kk = p * 16 + bk;
        float4 v = make_float4(0.f, 0.f, 0.f, 0.f);
        if (col < N) v = *(const float4*)(B + (size_t)(k0 + kk) * ldb + col);
        bR[p] = v;
    }
}

__device__ __forceinline__ void gemm_core(
        SMem& sm,
        const float* __restrict__ A, int lda, int pool_s, int gather,
        const float* __restrict__ B, int ldb,
        int M, int N, int bm, int bn, int ks, int kend,
        float (&acc)[8][4]) {
    int tid = threadIdx.x;
    int am = tid >> 3, akv = tid & 7;
    int bk = tid >> 4, bn4 = tid & 15;
    float inv_pool = 1.0f / (float)pool_s;

    float4 aR[4], bR[2];
    gc_stage(A, lda, pool_s, inv_pool, gather, B, ldb, M, N, bm, bn, ks,
             am, akv, bk, bn4, aR, bR);
    int nch = (kend - ks) / KCH;
    int tx = tid & 15, ty = tid >> 4;
    for (int c = 0; c < nch; ++c) {
        __syncthreads();
        #pragma unroll
        for (int p = 0; p < 4; ++p) {
            int m = p * 32 + am;
            sm.g.As[akv * 4 + 0][m] = aR[p].x;
            sm.g.As[akv * 4 + 1][m] = aR[p].y;
            sm.g.As[akv * 4 + 2][m] = aR[p].z;
            sm.g.As[akv * 4 + 3][m] = aR[p].w;
        }
        #pragma unroll
        for (int p = 0; p < 2; ++p)
            *(float4*)&sm.g.Bs[p * 16 + bk][bn4 * 4] = bR[p];
        __syncthreads();
        if (c + 1 < nch)
            gc_stage(A, lda, pool_s, inv_pool, gather, B, ldb, M, N, bm, bn,
                     ks + (c + 1) * KCH, am, akv, bk, bn4, aR, bR);
        #pragma unroll
        for (int kk = 0; kk < KCH; ++kk) {
            float4 b  = *(const float4*)&sm.g.Bs[kk][tx * 4];
            float4 al = *(const float4*)&sm.g.As[kk][ty * 8];
            float4 ah = *(const float4*)&sm.g.As[kk][ty * 8 + 4];
            float a8[8] = {al.x, al.y, al.z, al.w, ah.x, ah.y, ah.z, ah.w};
            float b4[4] = {b.x, b.y, b.z, b.w};
            #pragma unroll
            for (int u = 0; u < 8; ++u)
                #pragma unroll
                for (int v = 0; v < 4; ++v)
                    acc[u][v] += a8[u] * b4[v];
        }
    }
}

#define ACC_INIT(acc) { _Pragma("unroll") for (int u=0;u<8;++u) _Pragma("unroll") for (int v=0;v<4;++v) acc[u][v]=0.f; }

struct Params {
    const float *ln_in_b, *patch_W, *patch_b, *pos_emb;
    const float *Wq, *bq, *Wk, *bk, *Wv, *bv, *Wo, *bo, *Wc, *bc;
    const float *ln1_g, *ln1_b, *W1, *b1, *W2, *b2, *ln2_g, *ln2_b;
    const float *head_W, *head_b;
    float *out;
    float *h, *csum, *qkvAll, *oAll, *aAll, *f, *part, *headp;
    float *oPart, *mPart, *lPart, *qkvP;
    unsigned *bar;
};

// ======================= stage bodies =======================
__device__ void st_qkv_part(SMem& sm, const Params& p, int l, int u) {
    int scale, sp, y, x;
    if (u < 144)      { scale = 0; sp = u / 36; int r = u % 36; y = r / 9; x = r % 9; }
    else if (u < 216) { scale = 1; int v = u - 144; sp = v / 18; int r = v % 18; y = r / 9; x = r % 9; }
    else              { scale = 2; int v = u - 216; sp = v / 9; x = v % 9; y = 0; }
    int n = NN >> scale;
    int pool_s = 1 << scale;
    int bm = y * BM;
    int which = x / 3;
    int bn = (x % 3) * BN;
    size_t w = (size_t)(l * 3 + scale);
    const float* W = (which == 0) ? p.Wq : ((which == 1) ? p.Wk : p.Wv);
    float* outb = p.qkvP + (size_t)sp * 420000
                + (scale == 0 ? 0 : (scale == 1 ? 240000 : 360000));
    float acc[8][4];
    ACC_INIT(acc);
    gemm_core(sm, p.h, DD, pool_s, 0, W + w * DD * QKVN, QKVN, n, QKVN, bm, bn,
              sp * 128, sp * 128 + 128, acc);
    int tid = threadIdx.x, tx = tid & 15, ty = tid >> 4;
    int col = bn + tx * 4;
    if (col < QKVN) {
        #pragma unroll
        for (int uu = 0; uu < 8; ++uu) {
            int row = bm + ty * 8 + uu;
            if (row < n) {
                float4 o;
                o.x = acc[uu][0]; o.y = acc[uu][1]; o.z = acc[uu][2]; o.w = acc[uu][3];
                *(float4*)&outb[(size_t)row * QKV3 + which * QKVN + col] = o;
            }
        }
    }
}

__device__ void st_qkv_reduce(const Params& p, int l, int gtid, int gstride) {
    const float4* p0 = (const float4*)p.qkvP;
    float4* dst = (float4*)p.qkvAll;
    for (int i4 = gtid; i4 < 105000; i4 += gstride) {
        float4 a = p0[i4], b = p0[105000 + i4], c = p0[210000 + i4], d = p0[315000 + i4];
        int scale = (i4 < 60000) ? 0 : (i4 < 90000 ? 1 : 2);
        int rr = i4 % 120;
        int which = rr / 40, col4 = rr - which * 40;
        const float* bias = (which == 0) ? p.bq : (which == 1 ? p.bk : p.bv);
        float4 bb = ((const float4*)(bias + (size_t)(l * 3 + scale) * QKVN))[col4];
        float4 o;
        o.x = a.x + b.x + c.x + d.x + bb.x;
        o.y = a.y + b.y + c.y + d.y + bb.y;
        o.z = a.z + b.z + c.z + d.z + bb.z;
        o.w = a.w + b.w + c.w + d.w + bb.w;
        dst[i4] = o;
    }
}

__device__ void st_attn(SMem& sm, const Params& p, int u) {
    int scale, sp, qt, hh;
    if (u < 160)      { scale = 0; sp = u / 40; int r = u % 40; hh = r / 8; qt = r % 8; }
    else if (u < 200) { scale = 1; int v = u - 160; sp = v / 20; int r = v % 20; hh = r / 4; qt = r % 4; }
    else              { scale = 2; int v = u - 200; sp = 0; hh = v / 2; qt = v % 2; }
    int n = NN >> scale;
    int ks = sp * 128;
    int ke = min(n, ks + 128);
    const float* qkv = p.qkvAll + (scale == 0 ? 0 : (scale == 1 ? 240000 : 360000));
    int rowb = (scale == 0 ? 0 : (scale == 1 ? 500 : 750));

    int tid = threadIdx.x;
    int kg = tid & 7, qq = tid >> 3;
    int q0 = qt * 64 + qq, q1 = q0 + 32;
    bool ok0 = q0 < n, ok1 = q1 < n;

    float qa[32], qb[32];
    {
        const float* pa = qkv + (size_t)(ok0 ? q0 : 0) * QKV3 + hh * KDD;
        const float* pb = qkv + (size_t)(ok1 ? q1 : 0) * QKV3 + hh * KDD;
        #pragma unroll
        for (int c4 = 0; c4 < 8; ++c4) {
            float4 v0 = *(const float4*)(pa + c4 * 4);
            float4 v1 = *(const float4*)(pb + c4 * 4);
            qa[c4*4] = v0.x; qa[c4*4+1] = v0.y; qa[c4*4+2] = v0.z; qa[c4*4+3] = v0.w;
            qb[c4*4] = v1.x; qb[c4*4+1] = v1.y; qb[c4*4+2] = v1.z; qb[c4*4+3] = v1.w;
        }
    }
    float o0[32], o1[32];
    #pragma unroll
    for (int c = 0; c < 32; ++c) { o0[c] = 0.f; o1[c] = 0.f; }
    float m0 = -1e30f, m1 = -1e30f, l0 = 0.f, l1 = 0.f;
    int srow = tid >> 2, scol = tid & 3;

    for (int kc = ks; kc < ke; kc += 64) {
        __syncthreads();
        int krow = kc + srow;
        bool ok = krow < ke;
        const float* kp = qkv + (size_t)(ok ? krow : 0) * QKV3 + QKVN + hh * KDD;
        #pragma unroll
        for (int half = 0; half < 2; ++half) {
            int cc = (half * 4 + scol) * 4;
            float4 kv = ok ? *(const float4*)(kp + cc) : make_float4(0.f,0.f,0.f,0.f);
            float4 vv = ok ? *(const float4*)(kp + QKVN + cc) : make_float4(0.f,0.f,0.f,0.f);
            sm.a.Ks[srow][cc] = kv.x; sm.a.Ks[srow][cc+1] = kv.y;
            sm.a.Ks[srow][cc+2] = kv.z; sm.a.Ks[srow][cc+3] = kv.w;
            sm.a.Vs[srow][cc] = vv.x; sm.a.Vs[srow][cc+1] = vv.y;
            sm.a.Vs[srow][cc+2] = vv.z; sm.a.Vs[srow][cc+3] = vv.w;
        }
        __syncthreads();

        float pp0[8], pp1[8];
        float cm = -1e30f;
        #pragma unroll
        for (int jj = 0; jj < 8; ++jj) {
            int j = jj * 8 + kg;
            float s0 = 0.f, s1 = 0.f;
            #pragma unroll
            for (int c4 = 0; c4 < 8; ++c4) {
                float4 kv = *(const float4*)&sm.a.Ks[j][c4 * 4];
                s0 += qa[c4*4]*kv.x + qa[c4*4+1]*kv.y + qa[c4*4+2]*kv.z + qa[c4*4+3]*kv.w;
                s1 += qb[c4*4]*kv.x + qb[c4*4+1]*kv.y + qb[c4*4+2]*kv.z + qb[c4*4+3]*kv.w;
            }
            s0 *= 0.17677669529663687f;
            s1 *= 0.17677669529663687f;
            if (kc + j >= ke) { s0 = -1e30f; s1 = -1e30f; }
            pp0[jj] = s0; pp1[jj] = s1;
            cm = fmaxf(cm, fmaxf(s0, s1));
        }
        cm = fmaxf(cm, __shfl_xor(cm, 1));
        cm = fmaxf(cm, __shfl_xor(cm, 2));
        cm = fmaxf(cm, __shfl_xor(cm, 4));
        float mn0 = fmaxf(m0, cm), mn1 = fmaxf(m1, cm);
        float al0 = expf(m0 - mn0), al1 = expf(m1 - mn1);
        m0 = mn0; m1 = mn1;
        float ls0 = 0.f, ls1 = 0.f;
        #pragma unroll
        for (int jj = 0; jj < 8; ++jj) {
            pp0[jj] = expf(pp0[jj] - mn0); ls0 += pp0[jj];
            pp1[jj] = expf(pp1[jj] - mn1); ls1 += pp1[jj];
        }
        l0 = l0 * al0 + ls0;
        l1 = l1 * al1 + ls1;
        #pragma unroll
        for (int c = 0; c < 32; ++c) { o0[c] *= al0; o1[c] *= al1; }
        #pragma unroll
        for (int jj = 0; jj < 8; ++jj) {
            int j = jj * 8 + kg;
            float w0 = pp0[jj], w1 = pp1[jj];
            #pragma unroll
            for (int c4 = 0; c4 < 8; ++c4) {
                float4 vv = *(const float4*)&sm.a.Vs[j][c4 * 4];
                o0[c4*4]   += w0*vv.x; o0[c4*4+1] += w0*vv.y;
                o0[c4*4+2] += w0*vv.z; o0[c4*4+3] += w0*vv.w;
                o1[c4*4]   += w1*vv.x; o1[c4*4+1] += w1*vv.y;
                o1[c4*4+2] += w1*vv.z; o1[c4*4+3] += w1*vv.w;
            }
        }
    }
    #pragma unroll
    for (int st = 1; st < 8; st <<= 1) {
        l0 += __shfl_xor(l0, st);
        l1 += __shfl_xor(l1, st);
        #pragma unroll
        for (int c = 0; c < 32; ++c) {
            o0[c] += __shfl_xor(o0[c], st);
            o1[c] += __shfl_xor(o1[c], st);
        }
    }
    if (kg == 0) {
        float* ob = p.oPart + (size_t)sp * OSZ;
        if (ok0) {
            int r = rowb + q0;
            float* op = ob + (size_t)r * QKVN + hh * KDD;
            #pragma unroll
            for (int c4 = 0; c4 < 8; ++c4) {
                float4 v; v.x = o0[c4*4]; v.y = o0[c4*4+1]; v.z = o0[c4*4+2]; v.w = o0[c4*4+3];
                *(float4*)(op + c4 * 4) = v;
            }
            p.mPart[sp * MLSZ + r * HSC + hh] = m0;
            p.lPart[sp * MLSZ + r * HSC + hh] = l0;
        }
        if (ok1) {
            int r = rowb + q1;
            float* op = ob + (size_t)r * QKVN + hh * KDD;
            #pragma unroll
            for (int c4 = 0; c4 < 8; ++c4) {
                float4 v; v.x = o1[c4*4]; v.y = o1[c4*4+1]; v.z = o1[c4*4+2]; v.w = o1[c4*4+3];
                *(float4*)(op + c4 * 4) = v;
            }
            p.mPart[sp * MLSZ + r * HSC + hh] = m1;
            p.lPart[sp * MLSZ + r * HSC + hh] = l1;
        }
    }
}

__device__ void st_attn_combine(const Params& p, int gtid, int gstride) {
    for (int idx = gtid; idx < OSZ; idx += gstride) {
        int rh = idx >> 5;
        int r = rh / HSC, hh = rh - r * HSC;
        int scale = (r < 500) ? 0 : (r < 750 ? 1 : 2);
        int ns = 4 >> scale;
        float M = -1e30f;
        for (int s = 0; s < ns; ++s) M = fmaxf(M, p.mPart[s * MLSZ + r * HSC + hh]);
        float L = 0.f, val = 0.f;
        for (int s = 0; s < ns; ++s) {
            float wgt = expf(p.mPart[s * MLSZ + r * HSC + hh] - M);
            L += wgt * p.lPart[s * MLSZ + r * HSC + hh];
            val += wgt * p.oPart[(size_t)s * OSZ + idx];
        }
        p.oAll[idx] = val / L;
    }
}

__device__ void st_wo(SMem& sm, const Params& p, int l, int u) {
    int z, x, y;
    if (u < 32)      { z = 0; x = u % 8; y = u / 8; }
    else if (u < 48) { z = 1; int v = u - 32; x = v % 8; y = v / 8; }
    else             { z = 2; int v = u - 48; x = v % 8; y = 0; }
    int n = NN >> z;
    int bm = y * BM, bn = x * BN;
    size_t w = (size_t)(l * 3 + z);
    const float* A = p.oAll + (z == 0 ? 0 : (z == 1 ? 80000 : 120000));
    float* C = p.aAll + (z == 0 ? 0 : (z == 1 ? AOFF1 : AOFF2));
    const float* bias = p.bo + w * DD;
    float acc[8][4];
    ACC_INIT(acc);
    gemm_core(sm, A, QKVN, 1, 0, p.Wo + w * QKVN * DD, DD, n, DD, bm, bn, 0, QKVN, acc);
    int tid = threadIdx.x, tx = tid & 15, ty = tid >> 4;
    int col = bn + tx * 4;
    #pragma unroll
    for (int uu = 0; uu < 8; ++uu) {
        int row = bm + ty * 8 + uu;
        if (row < n) {
            float4 o;
            o.x = acc[uu][0] + bias[col];     o.y = acc[uu][1] + bias[col + 1];
            o.z = acc[uu][2] + bias[col + 2]; o.w = acc[uu][3] + bias[col + 3];
            *(float4*)&C[(size_t)row * DD + col] = o;
        }
    }
}

__device__ void st_comb(SMem& sm, const Params& p, const float* Wc, int u) {
    int x = u & 7, y = (u >> 3) & 3, zz = u >> 5;
    int bm = y * BM, bn = x * BN;
    float acc[8][4];
    ACC_INIT(acc);
    gemm_core(sm, p.aAll, DD, 1, 1, Wc, DD, NN, DD, bm, bn, zz * 256, zz * 256 + 256, acc);
    float* pz = p.part + (size_t)zz * NN * DD;
    int tid = threadIdx.x, tx = tid & 15, ty = tid >> 4;
    int col = bn + tx * 4;
    #pragma unroll
    for (int uu = 0; uu < 8; ++uu) {
        int row = bm + ty * 8 + uu;
        if (row < NN) {
            float4 o;
            o.x = acc[uu][0]; o.y = acc[uu][1]; o.z = acc[uu][2]; o.w = acc[uu][3];
            *(float4*)&pz[(size_t)row * DD + col] = o;
        }
    }
}

__device__ void st_w1(SMem& sm, const Params& p, const float* W1, int u) {
    int x = u & 31, y = (u >> 5) & 3, sp = u >> 7;
    int bm = y * BM, bn = x * BN;
    float acc[8][4];
    ACC_INIT(acc);
    gemm_core(sm, p.h, DD, 1, 0, W1, FF, NN, FF, bm, bn, sp * 256, sp * 256 + 256, acc);
    float* pz = p.part + (size_t)sp * NN * FF;
    int tid = threadIdx.x, tx = tid & 15, ty = tid >> 4;
    int col = bn + tx * 4;
    #pragma unroll
    for (int uu = 0; uu < 8; ++uu) {
        int row = bm + ty * 8 + uu;
        if (row < NN) {
            float4 o;
            o.x = acc[uu][0]; o.y = acc[uu][1]; o.z = acc[uu][2]; o.w = acc[uu][3];
            *(float4*)&pz[(size_t)row * FF + col] = o;
        }
    }
}

__device__ void st_w1_reduce(const Params& p, const float* b1, int gtid, int gstride) {
    const float4* pa = (const float4*)p.part;
    const float4* pb = (const float4*)(p.part + NN * FF);
    const float4* bb = (const float4*)b1;
    float4* dst = (float4*)p.f;
    for (int i4 = gtid; i4 < 256000; i4 += gstride) {
        float4 a = pa[i4], b = pb[i4], c = bb[i4 & 511];
        float4 o;
        o.x = gelu_exact(a.x + b.x + c.x);
        o.y = gelu_exact(a.y + b.y + c.y);
        o.z = gelu_exact(a.z + b.z + c.z);
        o.w = gelu_exact(a.w + b.w + c.w);
        dst[i4] = o;
    }
}

__device__ void st_w2(SMem& sm, const Params& p, const float* W2, int u) {
    int x = u & 7, y = (u >> 3) & 3, zz = u >> 5;
    int bm = y * BM, bn = x * BN;
    float acc[8][4];
    ACC_INIT(acc);
    gemm_core(sm, p.f, FF, 1, 0, W2, DD, NN, DD, bm, bn, zz * 256, zz * 256 + 256, acc);
    float* pz = p.part + (size_t)zz * NN * DD;
    int tid = threadIdx.x, tx = tid & 15, ty = tid >> 4;
    int col = bn + tx * 4;
    #pragma unroll
    for (int uu = 0; uu < 8; ++uu) {
        int row = bm + ty * 8 + uu;
        if (row < NN) {
            float4 o;
            o.x = acc[uu][0]; o.y = acc[uu][1]; o.z = acc[uu][2]; o.w = acc[uu][3];
            *(float4*)&pz[(size_t)row * DD + col] = o;
        }
    }
}

// 256 threads, one row: thread t handles cols t and t+256
__device__ void st_reduce_add_ln(SMem& sm, const Params& p, int S,
                                 const float* bias, const float* gw,
                                 const float* bw, int row) {
    int t = threadIdx.x;
    size_t i0 = (size_t)row * DD + t, i1 = i0 + 256;
    float x0 = p.h[i0] + bias[t];
    float x1 = p.h[i1] + bias[t + 256];
    for (int s = 0; s < S; ++s) {
        x0 += p.part[(size_t)s * NN * DD + i0];
        x1 += p.part[(size_t)s * NN * DD + i1];
    }
    float sum = x0 + x1, sq = x0 * x0 + x1 * x1;
    for (int off = 32; off; off >>= 1) {
        sum += __shfl_down(sum, off);
        sq  += __shfl_down(sq,  off);
    }
    int lane = t & 63, wv = t >> 6;
    if (lane == 0) { sm.ln.s1[wv] = sum; sm.ln.s2[wv] = sq; }
    __syncthreads();
    if (t == 0) {
        float a = sm.ln.s1[0] + sm.ln.s1[1] + sm.ln.s1[2] + sm.ln.s1[3];
        float b = sm.ln.s2[0] + sm.ln.s2[1] + sm.ln.s2[2] + sm.ln.s2[3];
        float mean = a / (float)DD;
        float var = b / (float)DD - mean * mean;
        sm.ln.mb[0] = mean;
        sm.ln.mb[1] = rsqrtf(var + LNEPS);
    }
    __syncthreads();
    float mean = sm.ln.mb[0], inv = sm.ln.mb[1];
    p.h[i0] = (x0 - mean) * inv * gw[t] + bw[t];
    p.h[i1] = (x1 - mean) * inv * gw[t + 256] + bw[t + 256];
    __syncthreads();
}

__device__ void st_head(SMem& sm, const Params& p) {
    int t = threadIdx.x;
    for (int d = t; d < DD; d += 256) {
        float s = 0.f;
        #pragma unroll
        for (int q = 0; q < 25; ++q) s += p.headp[(size_t)q * DD + d];
        sm.hd.gs[d] = s / (float)NN;
    }
    __syncthreads();
    float acc = p.head_b[t];
    #pragma unroll 16
    for (int d = 0; d < DD; ++d) acc += sm.hd.gs[d] * p.head_W[(size_t)d * NC + t];
    int lane = t & 63, wv = t >> 6;
    float mx = acc;
    for (int off = 32; off; off >>= 1) mx = fmaxf(mx, __shfl_down(mx, off));
    if (lane == 0) sm.hd.r[wv] = mx;
    __syncthreads();
    if (t == 0) sm.hd.bmx = fmaxf(fmaxf(sm.hd.r[0], sm.hd.r[1]), fmaxf(sm.hd.r[2], sm.hd.r[3]));
    __syncthreads();
    float e = expf(acc - sm.hd.bmx);
    float s = e;
    for (int off = 32; off; off >>= 1) s += __shfl_down(s, off);
    if (lane == 0) sm.hd.r[wv] = s;
    __syncthreads();
    if (t == 0) sm.hd.bsum = 1.f / (sm.hd.r[0] + sm.hd.r[1] + sm.hd.r[2] + sm.hd.r[3]);
    __syncthreads();
    float pv = e * sm.hd.bsum;
    for (int b = 0; b < NB; ++b) p.out[(size_t)b * NC + t] = pv;
}

// ======================= mega kernel =======================
__global__ __launch_bounds__(256) void mega(Params p) {
    __shared__ SMem sm;
    int b = blockIdx.x;
    int t = threadIdx.x;
    int gtid = b * 256 + t;
    const int gstride = 256 * 256;

    // S0: colsum (2 blocks)
    if (b < 2) {
        int d = b * 256 + t;
        float s = 0.f;
        for (int q = 0; q < 100; ++q) s += p.patch_W[q * DD + d];
        p.csum[d] = s;
    }
    gbar(p.bar);
    // S1: init h
    {
        float lnb = p.ln_in_b[0];
        for (int i = gtid; i < NN * DD; i += gstride) {
            int d = i & (DD - 1);
            p.h[i] = lnb * p.csum[d] + p.patch_b[d] + p.pos_emb[i];
        }
    }
    gbar(p.bar);

    for (int l = 0; l < NL; ++l) {
        if (b < 252) st_qkv_part(sm, p, l, b);
        gbar(p.bar);
        st_qkv_reduce(p, l, gtid, gstride);
        gbar(p.bar);
        if (b < 210) st_attn(sm, p, b);
        gbar(p.bar);
        st_attn_combine(p, gtid, gstride);
        gbar(p.bar);
        if (b < 56) st_wo(sm, p, l, b);
        gbar(p.bar);
        if (b < 192) st_comb(sm, p, p.Wc + (size_t)l * 3 * DD * DD, b);
        gbar(p.bar);
        for (int u = b; u < NN; u += 256)
            st_reduce_add_ln(sm, p, 6, p.bc + (size_t)l * DD,
                             p.ln1_g + (size_t)l * DD, p.ln1_b + (size_t)l * DD, u);
        gbar(p.bar);
        st_w1(sm, p, p.W1 + (size_t)l * DD * FF, b);
        gbar(p.bar);
        st_w1_reduce(p, p.b1 + (size_t)l * FF, gtid, gstride);
        gbar(p.bar);
        st_w2(sm, p, p.W2 + (size_t)l * FF * DD, b);
        gbar(p.bar);
        for (int u = b; u < NN; u += 256)
            st_reduce_add_ln(sm, p, 8, p.b2 + (size_t)l * DD,
                             p.ln2_g + (size_t)l * DD, p.ln2_b + (size_t)l * DD, u);
        gbar(p.bar);
    }
    // head: col-partial (50 units) then final on block 0
    if (b < 50) {
        int xb = b & 1, yb = b >> 1;
        int col = xb * 256 + t;
        int r0 = yb * 20;
        float s = 0.f;
        #pragma unroll
        for (int r = 0; r < 20; ++r) s += p.h[(size_t)(r0 + r) * DD + col];
        p.headp[(size_t)yb * DD + col] = s;
    }
    gbar(p.bar);
    if (b == 0) st_head(sm, p);
}

extern "C" void kernel_launch(void* const* d_in, const int* in_sizes, int n_in,
                              void* d_out, int out_size, void* d_ws, size_t ws_size,
                              hipStream_t stream) {
    Params p;
    p.ln_in_b = (const float*)d_in[2];
    p.patch_W = (const float*)d_in[3];
    p.patch_b = (const float*)d_in[4];
    p.pos_emb = (const float*)d_in[5];
    p.Wq = (const float*)d_in[6];  p.bq = (const float*)d_in[7];
    p.Wk = (const float*)d_in[8];  p.bk = (const float*)d_in[9];
    p.Wv = (const float*)d_in[10]; p.bv = (const float*)d_in[11];
    p.Wo = (const float*)d_in[12]; p.bo = (const float*)d_in[13];
    p.Wc = (const float*)d_in[14]; p.bc = (const float*)d_in[15];
    p.ln1_g = (const float*)d_in[16]; p.ln1_b = (const float*)d_in[17];
    p.W1 = (const float*)d_in[18]; p.b1 = (const float*)d_in[19];
    p.W2 = (const float*)d_in[20]; p.b2 = (const float*)d_in[21];
    p.ln2_g = (const float*)d_in[22]; p.ln2_b = (const float*)d_in[23];
    p.head_W = (const float*)d_in[24]; p.head_b = (const float*)d_in[25];
    p.out = (float*)d_out;

    float* ws = (float*)d_ws;
    p.h      = ws;
    p.csum   = p.h + 256000;
    p.qkvAll = p.csum + 1024;
    p.oAll   = p.qkvAll + 420000;
    p.aAll   = p.oAll + 140000;
    p.f      = p.aAll + 448000;
    p.part   = p.f + 1024000;
    p.headp  = p.part + 2048000;
    p.oPart  = p.f;
    p.mPart  = p.f + 560000;
    p.lPart  = p.mPart + 4 * MLSZ;
    p.qkvP   = p.part;
    p.bar    = (unsigned*)(p.headp + 12800);

    hipMemsetAsync(p.bar, 0, 64, stream);
    mega<<<dim3(NBLK), dim3(256), 0, stream>>>(p);
}

// Round 9
// 1245.844 us; speedup vs baseline: 2.6966x; 2.2514x over previous
//
#include <hip/hip_runtime.h>
#include <math.h>

// Model constants: B=32, T=50000, P=100, D=512, H=16, L=6, C=256
// SCALES=[1,2,4], HS=5 heads/scale, KD=32, N=500 patches, FF=2048, EPS=1e-3.
//
// KEY INSIGHT (round 0, verified): first layernorm is over a size-1 axis ->
// output == ln_in_b[0] everywhere. h is batch-independent; network runs once
// on (500 x 512); final row broadcast x32.
//
// Round 9: persistent-kernel experiment CLOSED. R7/R8 proved the software
// grid barrier's required __threadfence (L2 invalidate on every block) costs
// ~22-30us/barrier on non-coherent XCD L2s (FETCH 373MB both rounds) —
// worse than hardware launch boundaries. Revert to R5 multi-launch (1074us)
// and cut launches 76 -> 58: qkv_reduce fused into attn_split (partials
// summed at Q/K/V staging), w1_direct with fused bias+gelu (no split-K).

#define DD 512
#define NN 500
#define HSC 5
#define KDD 32
#define QKVN 160
#define QKV3 480
#define FF 2048
#define NL 6
#define NC 256
#define NB 32
#define LNEPS 1e-3f
#define BM 128
#define BN 64
#define KCH 32

// aAll sub-buffer offsets (floats)
#define AOFF1 256000
#define AOFF2 384000
#define RTOT 875
#define OSZ 140000
#define MLSZ 4384
#define QPSTRIDE 420000   // one qkv split-K partial (875 rows x 480)

__device__ __forceinline__ float gelu_exact(float x) {
    return 0.5f * x * (1.0f + erff(x * 0.70710678118654752f));
}

// ======================= GEMM core (R3-verified engine) =======================
__device__ __forceinline__ void gc_stage(
        const float* __restrict__ A, int lda, int pool_s, float inv_pool, int gather,
        const float* __restrict__ B, int ldb,
        int M, int N, int bm, int bn, int k0,
        int am, int akv, int bk, int bn4, float4* aR, float4* bR) {
    if (!gather) {
        #pragma unroll
        for (int p = 0; p < 4; ++p) {
            int row = bm + p * 32 + am;
            float4 v = make_float4(0.f, 0.f, 0.f, 0.f);
            if (row < M) {
                const float* ap = A + (size_t)row * pool_s * lda + k0 + akv * 4;
                v = *(const float4*)ap;
                for (int t = 1; t < pool_s; ++t) {
                    float4 u = *(const float4*)(ap + (size_t)t * lda);
                    v.x += u.x; v.y += u.y; v.z += u.z; v.w += u.w;
                }
                v.x *= inv_pool; v.y *= inv_pool; v.z *= inv_pool; v.w *= inv_pool;
            }
            aR[p] = v;
        }
    } else {
        int si = k0 >> 9;
        int dd0 = k0 & (DD - 1);
        const float* ap0 = A + (si == 0 ? 0 : (si == 1 ? AOFF1 : AOFF2));
        #pragma unroll
        for (int p = 0; p < 4; ++p) {
            int row = bm + p * 32 + am;
            float4 v = make_float4(0.f, 0.f, 0.f, 0.f);
            if (row < M)
                v = *(const float4*)(ap0 + (size_t)(row >> si) * DD + dd0 + akv * 4);
            aR[p] = v;
        }
    }
    int col = bn + bn4 * 4;
    #pragma unroll
    for (int p = 0; p < 2; ++p) {
        int kk = p * 16 + bk;
        float4 v = make_float4(0.f, 0.f, 0.f, 0.f);
        if (col < N) v = *(const float4*)(B + (size_t)(k0 + kk) * ldb + col);
        bR[p] = v;
    }
}

__device__ __forceinline__ void gemm_core(
        const float* __restrict__ A, int lda, int pool_s, int gather,
        const float* __restrict__ B, int ldb,
        int M, int N, int bm, int bn, int ks, int kend,
        float (&acc)[8][4]) {
    __shared__ float As[KCH][132];
    __shared__ float Bs[KCH][68];
    int tid = threadIdx.x;
    int am = tid >> 3, akv = tid & 7;
    int bk = tid >> 4, bn4 = tid & 15;
    float inv_pool = 1.0f / (float)pool_s;

    float4 aR[4], bR[2];
    gc_stage(A, lda, pool_s, inv_pool, gather, B, ldb, M, N, bm, bn, ks,
             am, akv, bk, bn4, aR, bR);
    int nch = (kend - ks) / KCH;
    int tx = tid & 15, ty = tid >> 4;
    for (int c = 0; c < nch; ++c) {
        __syncthreads();
        #pragma unroll
        for (int p = 0; p < 4; ++p) {
            int m = p * 32 + am;
            As[akv * 4 + 0][m] = aR[p].x;
            As[akv * 4 + 1][m] = aR[p].y;
            As[akv * 4 + 2][m] = aR[p].z;
            As[akv * 4 + 3][m] = aR[p].w;
        }
        #pragma unroll
        for (int p = 0; p < 2; ++p)
            *(float4*)&Bs[p * 16 + bk][bn4 * 4] = bR[p];
        __syncthreads();
        if (c + 1 < nch)
            gc_stage(A, lda, pool_s, inv_pool, gather, B, ldb, M, N, bm, bn,
                     ks + (c + 1) * KCH, am, akv, bk, bn4, aR, bR);
        #pragma unroll
        for (int kk = 0; kk < KCH; ++kk) {
            float4 b  = *(const float4*)&Bs[kk][tx * 4];
            float4 al = *(const float4*)&As[kk][ty * 8];
            float4 ah = *(const float4*)&As[kk][ty * 8 + 4];
            float a8[8] = {al.x, al.y, al.z, al.w, ah.x, ah.y, ah.z, ah.w};
            float b4[4] = {b.x, b.y, b.z, b.w};
            #pragma unroll
            for (int u = 0; u < 8; ++u)
                #pragma unroll
                for (int v = 0; v < 4; ++v)
                    acc[u][v] += a8[u] * b4[v];
        }
    }
}

#define ACC_INIT(acc) { _Pragma("unroll") for (int u=0;u<8;++u) _Pragma("unroll") for (int v=0;v<4;++v) acc[u][v]=0.f; }

// ======================= setup =======================
__global__ void colsum_kernel(const float* __restrict__ pw, float* __restrict__ csum) {
    int d = blockIdx.x * blockDim.x + threadIdx.x;
    if (d < DD) {
        float s = 0.f;
        for (int p = 0; p < 100; ++p) s += pw[p * DD + d];
        csum[d] = s;
    }
}

__global__ void init_h(const float* __restrict__ csum, const float* __restrict__ pb,
                       const float* __restrict__ pos, const float* __restrict__ lnb,
                       float* __restrict__ h) {
    int idx = blockIdx.x * 256 + threadIdx.x;
    if (idx >= NN * DD) return;
    int d = idx & (DD - 1);
    h[idx] = lnb[0] * csum[d] + pb[d] + pos[idx];
}

// ======================= QKV partial (all scales, k-split S=4) =======================
// grid (9, 4, 12): x = which*3 + coltile, y = row tile, z = scale*4 + sp (kq=128)
__global__ __launch_bounds__(256) void qkv_part(
        const float* __restrict__ h,
        const float* __restrict__ Wq, const float* __restrict__ Wk,
        const float* __restrict__ Wv,
        float* __restrict__ part, int l) {
    int scale = blockIdx.z >> 2, sp = blockIdx.z & 3;
    int n = NN >> scale;
    int pool_s = 1 << scale;
    int bm = blockIdx.y * BM;
    if (bm >= n) return;
    int which = blockIdx.x / 3;
    int bn = (blockIdx.x % 3) * BN;
    size_t w = (size_t)(l * 3 + scale);
    const float* W = (which == 0) ? Wq : ((which == 1) ? Wk : Wv);
    float* outb = part + (size_t)sp * QPSTRIDE
                + (scale == 0 ? 0 : (scale == 1 ? 240000 : 360000));

    float acc[8][4];
    ACC_INIT(acc);
    gemm_core(h, DD, pool_s, 0, W + w * DD * QKVN, QKVN, n, QKVN, bm, bn,
              sp * 128, sp * 128 + 128, acc);

    int tid = threadIdx.x, tx = tid & 15, ty = tid >> 4;
    int col = bn + tx * 4;
    if (col < QKVN) {
        #pragma unroll
        for (int u = 0; u < 8; ++u) {
            int row = bm + ty * 8 + u;
            if (row < n) {
                float4 o;
                o.x = acc[u][0]; o.y = acc[u][1]; o.z = acc[u][2]; o.w = acc[u][3];
                *(float4*)&outb[(size_t)row * QKV3 + which * QKVN + col] = o;
            }
        }
    }
}

// sum of the 4 qkv split-K partials at a float4 offset
__device__ __forceinline__ float4 qp_sum4(const float* __restrict__ qkvP, size_t idx) {
    float4 a = *(const float4*)(qkvP + idx);
    float4 b = *(const float4*)(qkvP + QPSTRIDE + idx);
    float4 c = *(const float4*)(qkvP + 2 * QPSTRIDE + idx);
    float4 d = *(const float4*)(qkvP + 3 * QPSTRIDE + idx);
    return make_float4(a.x + b.x + c.x + d.x, a.y + b.y + c.y + d.y,
                       a.z + b.z + c.z + d.z, a.w + b.w + c.w + d.w);
}

// ======================= attention: key-split flash, qkv-reduce fused =======================
// grid (8, 5, 7): x = 64-query tile, y = head, z -> (scale, key-split).
// Reads the 4 qkv partials directly (+bias) — qkvAll never materialized.
__global__ __launch_bounds__(256) void attn_split(
        const float* __restrict__ qkvP,
        const float* __restrict__ bq, const float* __restrict__ bk,
        const float* __restrict__ bv, int l,
        float* __restrict__ oPart,
        float* __restrict__ mPart, float* __restrict__ lPart) {
    int z = blockIdx.z;
    int scale, sp;
    if (z < 4)      { scale = 0; sp = z; }
    else if (z < 6) { scale = 1; sp = z - 4; }
    else            { scale = 2; sp = 0; }
    int n = NN >> scale;
    int qt = blockIdx.x;
    if (qt * 64 >= n) return;
    int hh = blockIdx.y;
    int ks = sp * 128;
    int ke = min(n, ks + 128);
    size_t scaleoff = (scale == 0 ? 0 : (scale == 1 ? 240000 : 360000));
    int rowb = (scale == 0 ? 0 : (scale == 1 ? 500 : 750));
    size_t wb = (size_t)(l * 3 + scale) * QKVN + hh * KDD;

    int tid = threadIdx.x;
    int kg = tid & 7, qq = tid >> 3;
    int q0 = qt * 64 + qq, q1 = q0 + 32;
    bool ok0 = q0 < n, ok1 = q1 < n;

    float qa[32], qb_[32];
    {
        size_t i0 = scaleoff + (size_t)(ok0 ? q0 : 0) * QKV3 + hh * KDD;
        size_t i1 = scaleoff + (size_t)(ok1 ? q1 : 0) * QKV3 + hh * KDD;
        #pragma unroll
        for (int c4 = 0; c4 < 8; ++c4) {
            float4 bqv = *(const float4*)(bq + wb + c4 * 4);
            float4 v0 = qp_sum4(qkvP, i0 + c4 * 4);
            float4 v1 = qp_sum4(qkvP, i1 + c4 * 4);
            qa[c4*4] = v0.x + bqv.x; qa[c4*4+1] = v0.y + bqv.y;
            qa[c4*4+2] = v0.z + bqv.z; qa[c4*4+3] = v0.w + bqv.w;
            qb_[c4*4] = v1.x + bqv.x; qb_[c4*4+1] = v1.y + bqv.y;
            qb_[c4*4+2] = v1.z + bqv.z; qb_[c4*4+3] = v1.w + bqv.w;
        }
    }

    __shared__ float Ks[64][36];
    __shared__ float Vs[64][36];
    float o0[32], o1[32];
    #pragma unroll
    for (int c = 0; c < 32; ++c) { o0[c] = 0.f; o1[c] = 0.f; }
    float m0 = -1e30f, m1 = -1e30f, l0 = 0.f, l1 = 0.f;
    int srow = tid >> 2, scol = tid & 3;

    for (int kc = ks; kc < ke; kc += 64) {
        __syncthreads();
        int krow = kc + srow;
        bool ok = krow < ke;
        size_t kbase = scaleoff + (size_t)(ok ? krow : 0) * QKV3 + QKVN + hh * KDD;
        #pragma unroll
        for (int half = 0; half < 2; ++half) {
            int cc = (half * 4 + scol) * 4;
            float4 kv = make_float4(0.f, 0.f, 0.f, 0.f);
            float4 vv = make_float4(0.f, 0.f, 0.f, 0.f);
            if (ok) {
                float4 bkv = *(const float4*)(bk + wb + cc);
                float4 bvv = *(const float4*)(bv + wb + cc);
                kv = qp_sum4(qkvP, kbase + cc);
                vv = qp_sum4(qkvP, kbase + QKVN + cc);
                kv.x += bkv.x; kv.y += bkv.y; kv.z += bkv.z; kv.w += bkv.w;
                vv.x += bvv.x; vv.y += bvv.y; vv.z += bvv.z; vv.w += bvv.w;
            }
            Ks[srow][cc] = kv.x; Ks[srow][cc+1] = kv.y; Ks[srow][cc+2] = kv.z; Ks[srow][cc+3] = kv.w;
            Vs[srow][cc] = vv.x; Vs[srow][cc+1] = vv.y; Vs[srow][cc+2] = vv.z; Vs[srow][cc+3] = vv.w;
        }
        __syncthreads();

        float p0[8], p1[8];
        float cm = -1e30f;
        #pragma unroll
        for (int jj = 0; jj < 8; ++jj) {
            int j = jj * 8 + kg;
            float s0 = 0.f, s1 = 0.f;
            #pragma unroll
            for (int c4 = 0; c4 < 8; ++c4) {
                float4 kv = *(const float4*)&Ks[j][c4 * 4];
                s0 += qa[c4*4]*kv.x + qa[c4*4+1]*kv.y + qa[c4*4+2]*kv.z + qa[c4*4+3]*kv.w;
                s1 += qb_[c4*4]*kv.x + qb_[c4*4+1]*kv.y + qb_[c4*4+2]*kv.z + qb_[c4*4+3]*kv.w;
            }
            s0 *= 0.17677669529663687f;
            s1 *= 0.17677669529663687f;
            if (kc + j >= ke) { s0 = -1e30f; s1 = -1e30f; }
            p0[jj] = s0; p1[jj] = s1;
            cm = fmaxf(cm, fmaxf(s0, s1));
        }
        cm = fmaxf(cm, __shfl_xor(cm, 1));
        cm = fmaxf(cm, __shfl_xor(cm, 2));
        cm = fmaxf(cm, __shfl_xor(cm, 4));
        float mn0 = fmaxf(m0, cm), mn1 = fmaxf(m1, cm);
        float al0 = expf(m0 - mn0), al1 = expf(m1 - mn1);
        m0 = mn0; m1 = mn1;
        float ls0 = 0.f, ls1 = 0.f;
        #pragma unroll
        for (int jj = 0; jj < 8; ++jj) {
            p0[jj] = expf(p0[jj] - mn0); ls0 += p0[jj];
            p1[jj] = expf(p1[jj] - mn1); ls1 += p1[jj];
        }
        l0 = l0 * al0 + ls0;
        l1 = l1 * al1 + ls1;
        #pragma unroll
        for (int c = 0; c < 32; ++c) { o0[c] *= al0; o1[c] *= al1; }
        #pragma unroll
        for (int jj = 0; jj < 8; ++jj) {
            int j = jj * 8 + kg;
            float w0 = p0[jj], w1 = p1[jj];
            #pragma unroll
            for (int c4 = 0; c4 < 8; ++c4) {
                float4 vv = *(const float4*)&Vs[j][c4 * 4];
                o0[c4*4]   += w0*vv.x; o0[c4*4+1] += w0*vv.y;
                o0[c4*4+2] += w0*vv.z; o0[c4*4+3] += w0*vv.w;
                o1[c4*4]   += w1*vv.x; o1[c4*4+1] += w1*vv.y;
                o1[c4*4+2] += w1*vv.z; o1[c4*4+3] += w1*vv.w;
            }
        }
    }
    #pragma unroll
    for (int st = 1; st < 8; st <<= 1) {
        l0 += __shfl_xor(l0, st);
        l1 += __shfl_xor(l1, st);
        #pragma unroll
        for (int c = 0; c < 32; ++c) {
            o0[c] += __shfl_xor(o0[c], st);
            o1[c] += __shfl_xor(o1[c], st);
        }
    }
    if (kg == 0) {
        float* ob = oPart + (size_t)sp * OSZ;
        if (ok0) {
            int r = rowb + q0;
            float* op = ob + (size_t)r * QKVN + hh * KDD;
            #pragma unroll
            for (int c4 = 0; c4 < 8; ++c4) {
                float4 v; v.x = o0[c4*4]; v.y = o0[c4*4+1]; v.z = o0[c4*4+2]; v.w = o0[c4*4+3];
                *(float4*)(op + c4 * 4) = v;
            }
            mPart[sp * MLSZ + r * HSC + hh] = m0;
            lPart[sp * MLSZ + r * HSC + hh] = l0;
        }
        if (ok1) {
            int r = rowb + q1;
            float* op = ob + (size_t)r * QKVN + hh * KDD;
            #pragma unroll
            for (int c4 = 0; c4 < 8; ++c4) {
                float4 v; v.x = o1[c4*4]; v.y = o1[c4*4+1]; v.z = o1[c4*4+2]; v.w = o1[c4*4+3];
                *(float4*)(op + c4 * 4) = v;
            }
            mPart[sp * MLSZ + r * HSC + hh] = m1;
            lPart[sp * MLSZ + r * HSC + hh] = l1;
        }
    }
}

__global__ void attn_combine(const float* __restrict__ oPart,
                             const float* __restrict__ mPart,
                             const float* __restrict__ lPart,
                             float* __restrict__ oAll) {
    int idx = blockIdx.x * 256 + threadIdx.x;
    if (idx >= OSZ) return;
    int rh = idx >> 5;
    int r = rh / HSC, hh = rh - r * HSC;
    int scale = (r < 500) ? 0 : (r < 750 ? 1 : 2);
    int ns = 4 >> scale;
    float M = -1e30f;
    for (int s = 0; s < ns; ++s) M = fmaxf(M, mPart[s * MLSZ + r * HSC + hh]);
    float L = 0.f, val = 0.f;
    for (int s = 0; s < ns; ++s) {
        float wgt = expf(mPart[s * MLSZ + r * HSC + hh] - M);
        L += wgt * lPart[s * MLSZ + r * HSC + hh];
        val += wgt * oPart[(size_t)s * OSZ + idx];
    }
    oAll[idx] = val / L;
}

// ======================= Wo (all scales, bias fused) =======================
__global__ __launch_bounds__(256) void wo_all(
        const float* __restrict__ oAll, const float* __restrict__ Wo,
        const float* __restrict__ bo, float* __restrict__ aAll, int l) {
    int z = blockIdx.z;
    int n = NN >> z;
    if ((int)blockIdx.y * BM >= n) return;
    int bm = blockIdx.y * BM, bn = blockIdx.x * BN;
    size_t w = (size_t)(l * 3 + z);
    const float* A = oAll + (z == 0 ? 0 : (z == 1 ? 80000 : 120000));
    float* C = aAll + (z == 0 ? 0 : (z == 1 ? AOFF1 : AOFF2));
    const float* bias = bo + w * DD;

    float acc[8][4];
    ACC_INIT(acc);
    gemm_core(A, QKVN, 1, 0, Wo + w * QKVN * DD, DD, n, DD, bm, bn, 0, QKVN, acc);

    int tid = threadIdx.x, tx = tid & 15, ty = tid >> 4;
    int col = bn + tx * 4;
    #pragma unroll
    for (int u = 0; u < 8; ++u) {
        int row = bm + ty * 8 + u;
        if (row < n) {
            float4 o;
            o.x = acc[u][0] + bias[col];     o.y = acc[u][1] + bias[col + 1];
            o.z = acc[u][2] + bias[col + 2]; o.w = acc[u][3] + bias[col + 3];
            *(float4*)&C[(size_t)row * DD + col] = o;
        }
    }
}

// ======================= comb partial (gather-A) =======================
__global__ __launch_bounds__(256) void comb_part(
        const float* __restrict__ aAll, const float* __restrict__ Wc,
        float* __restrict__ part) {
    int zz = blockIdx.z;
    int bm = blockIdx.y * BM, bn = blockIdx.x * BN;
    float acc[8][4];
    ACC_INIT(acc);
    gemm_core(aAll, DD, 1, 1, Wc, DD, NN, DD, bm, bn, zz * 256, zz * 256 + 256, acc);
    float* pz = part + (size_t)zz * NN * DD;
    int tid = threadIdx.x, tx = tid & 15, ty = tid >> 4;
    int col = bn + tx * 4;
    #pragma unroll
    for (int u = 0; u < 8; ++u) {
        int row = bm + ty * 8 + u;
        if (row < NN) {
            float4 o;
            o.x = acc[u][0]; o.y = acc[u][1]; o.z = acc[u][2]; o.w = acc[u][3];
            *(float4*)&pz[(size_t)row * DD + col] = o;
        }
    }
}

// ======================= W1 direct (bias+gelu fused) =======================
// grid (32, 4)
__global__ __launch_bounds__(256) void w1_direct(
        const float* __restrict__ h, const float* __restrict__ W1,
        const float* __restrict__ b1, float* __restrict__ f) {
    int bm = blockIdx.y * BM, bn = blockIdx.x * BN;
    float acc[8][4];
    ACC_INIT(acc);
    gemm_core(h, DD, 1, 0, W1, FF, NN, FF, bm, bn, 0, DD, acc);
    int tid = threadIdx.x, tx = tid & 15, ty = tid >> 4;
    int col = bn + tx * 4;
    #pragma unroll
    for (int u = 0; u < 8; ++u) {
        int row = bm + ty * 8 + u;
        if (row < NN) {
            float4 o;
            o.x = gelu_exact(acc[u][0] + b1[col]);
            o.y = gelu_exact(acc[u][1] + b1[col + 1]);
            o.z = gelu_exact(acc[u][2] + b1[col + 2]);
            o.w = gelu_exact(acc[u][3] + b1[col + 3]);
            *(float4*)&f[(size_t)row * FF + col] = o;
        }
    }
}

// ======================= W2 partial =======================
__global__ __launch_bounds__(256) void w2_part(
        const float* __restrict__ f, const float* __restrict__ W2,
        float* __restrict__ part) {
    int zz = blockIdx.z;
    int bm = blockIdx.y * BM, bn = blockIdx.x * BN;
    float acc[8][4];
    ACC_INIT(acc);
    gemm_core(f, FF, 1, 0, W2, DD, NN, DD, bm, bn, zz * 256, zz * 256 + 256, acc);
    float* pz = part + (size_t)zz * NN * DD;
    int tid = threadIdx.x, tx = tid & 15, ty = tid >> 4;
    int col = bn + tx * 4;
    #pragma unroll
    for (int u = 0; u < 8; ++u) {
        int row = bm + ty * 8 + u;
        if (row < NN) {
            float4 o;
            o.x = acc[u][0]; o.y = acc[u][1]; o.z = acc[u][2]; o.w = acc[u][3];
            *(float4*)&pz[(size_t)row * DD + col] = o;
        }
    }
}

// ======================= fused reduce + bias + residual + LN =======================
__global__ void reduce_add_ln(const float* __restrict__ part, int S,
                              const float* __restrict__ bias,
                              float* __restrict__ h,
                              const float* __restrict__ gw,
                              const float* __restrict__ bw) {
    int row = blockIdx.x, t = threadIdx.x;
    size_t idx = (size_t)row * DD + t;
    float x = h[idx] + bias[t];
    for (int s = 0; s < S; ++s) x += part[(size_t)s * NN * DD + idx];
    int lane = t & 63, wv = t >> 6;
    __shared__ float s1[8], s2[8];
    __shared__ float mb[2];
    float sum = x, sq = x * x;
    for (int off = 32; off; off >>= 1) {
        sum += __shfl_down(sum, off);
        sq  += __shfl_down(sq,  off);
    }
    if (lane == 0) { s1[wv] = sum; s2[wv] = sq; }
    __syncthreads();
    if (t == 0) {
        float a = 0.f, b = 0.f;
        for (int i = 0; i < 8; ++i) { a += s1[i]; b += s2[i]; }
        float mean = a / (float)DD;
        float var = b / (float)DD - mean * mean;
        mb[0] = mean;
        mb[1] = rsqrtf(var + LNEPS);
    }
    __syncthreads();
    h[idx] = (x - mb[0]) * mb[1] * gw[t] + bw[t];
}

// ======================= head =======================
__global__ void col_mean_part(const float* __restrict__ h, float* __restrict__ partial) {
    int col = blockIdx.x * 256 + threadIdx.x;
    int r0 = blockIdx.y * 20;
    float s = 0.f;
    #pragma unroll
    for (int r = 0; r < 20; ++r) s += h[(size_t)(r0 + r) * DD + col];
    partial[(size_t)blockIdx.y * DD + col] = s;
}

__global__ void head_kernel(const float* __restrict__ partial,
                            const float* __restrict__ hw,
                            const float* __restrict__ hb, float* __restrict__ out) {
    __shared__ float gs[DD];
    __shared__ float r[4];
    __shared__ float bmx, bsum;
    int t = threadIdx.x;
    for (int d = t; d < DD; d += 256) {
        float s = 0.f;
        #pragma unroll
        for (int p = 0; p < 25; ++p) s += partial[(size_t)p * DD + d];
        gs[d] = s / (float)NN;
    }
    __syncthreads();
    float acc = hb[t];
    #pragma unroll 16
    for (int d = 0; d < DD; ++d) acc += gs[d] * hw[(size_t)d * NC + t];
    int lane = t & 63, wv = t >> 6;
    float mx = acc;
    for (int off = 32; off; off >>= 1) mx = fmaxf(mx, __shfl_down(mx, off));
    if (lane == 0) r[wv] = mx;
    __syncthreads();
    if (t == 0) bmx = fmaxf(fmaxf(r[0], r[1]), fmaxf(r[2], r[3]));
    __syncthreads();
    float e = expf(acc - bmx);
    float s = e;
    for (int off = 32; off; off >>= 1) s += __shfl_down(s, off);
    if (lane == 0) r[wv] = s;
    __syncthreads();
    if (t == 0) bsum = 1.f / (r[0] + r[1] + r[2] + r[3]);
    __syncthreads();
    float pv = e * bsum;
    for (int b = 0; b < NB; ++b) out[(size_t)b * NC + t] = pv;
}

extern "C" void kernel_launch(void* const* d_in, const int* in_sizes, int n_in,
                              void* d_out, int out_size, void* d_ws, size_t ws_size,
                              hipStream_t stream) {
    const float* ln_in_b = (const float*)d_in[2];
    const float* patch_W = (const float*)d_in[3];
    const float* patch_b = (const float*)d_in[4];
    const float* pos_emb = (const float*)d_in[5];
    const float* Wq = (const float*)d_in[6];
    const float* bq = (const float*)d_in[7];
    const float* Wk = (const float*)d_in[8];
    const float* bk = (const float*)d_in[9];
    const float* Wv = (const float*)d_in[10];
    const float* bv = (const float*)d_in[11];
    const float* Wo = (const float*)d_in[12];
    const float* bo = (const float*)d_in[13];
    const float* Wc = (const float*)d_in[14];
    const float* bc = (const float*)d_in[15];
    const float* ln1_g = (const float*)d_in[16];
    const float* ln1_b = (const float*)d_in[17];
    const float* W1 = (const float*)d_in[18];
    const float* b1 = (const float*)d_in[19];
    const float* W2 = (const float*)d_in[20];
    const float* b2 = (const float*)d_in[21];
    const float* ln2_g = (const float*)d_in[22];
    const float* ln2_b = (const float*)d_in[23];
    const float* head_W = (const float*)d_in[24];
    const float* head_b = (const float*)d_in[25];
    float* out = (float*)d_out;

    // workspace (floats); qkvP aliases part, oPart/ml alias f (R5 layout).
    float* ws = (float*)d_ws;
    float* h      = ws;                  // 256000
    float* csum   = h + 256000;          // 1024
    float* oAll   = csum + 1024;         // 140000
    float* aAll   = oAll + 140000;       // 448000
    float* f      = aAll + 448000;       // 1024000 (also oPart+ml between attn/combine)
    float* part   = f + 1024000;         // 2048000 (also qkvP 1680000)
    float* headp  = part + 2048000;      // 12800
    float* oPart  = f;                   // 4*140000
    float* mPart  = f + 560000;          // 4*MLSZ
    float* lPart  = mPart + 4 * MLSZ;    // 4*MLSZ
    float* qkvP   = part;

    colsum_kernel<<<1, 512, 0, stream>>>(patch_W, csum);
    init_h<<<(NN * DD + 255) / 256, 256, 0, stream>>>(csum, patch_b, pos_emb, ln_in_b, h);

    for (int l = 0; l < NL; ++l) {
        qkv_part<<<dim3(9, 4, 12), 256, 0, stream>>>(h, Wq, Wk, Wv, qkvP, l);
        attn_split<<<dim3(8, HSC, 7), 256, 0, stream>>>(qkvP, bq, bk, bv, l,
                                                        oPart, mPart, lPart);
        attn_combine<<<(OSZ + 255) / 256, 256, 0, stream>>>(oPart, mPart, lPart, oAll);
        wo_all<<<dim3(8, 4, 3), 256, 0, stream>>>(oAll, Wo, bo, aAll, l);
        comb_part<<<dim3(8, 4, 6), 256, 0, stream>>>(
            aAll, Wc + (size_t)l * 3 * DD * DD, part);
        reduce_add_ln<<<NN, DD, 0, stream>>>(part, 6, bc + (size_t)l * DD, h,
                                             ln1_g + (size_t)l * DD, ln1_b + (size_t)l * DD);
        w1_direct<<<dim3(32, 4), 256, 0, stream>>>(
            h, W1 + (size_t)l * DD * FF, b1 + (size_t)l * FF, f);
        w2_part<<<dim3(8, 4, 8), 256, 0, stream>>>(f, W2 + (size_t)l * FF * DD, part);
        reduce_add_ln<<<NN, DD, 0, stream>>>(part, 8, b2 + (size_t)l * DD, h,
                                             ln2_g + (size_t)l * DD, ln2_b + (size_t)l * DD);
    }
    col_mean_part<<<dim3(2, 25), 256, 0, stream>>>(h, headp);
    head_kernel<<<1, 256, 0, stream>>>(headp, head_W, head_b, out);
}